// Round 10
// baseline (579.134 us; speedup 1.0000x reference)
//
#include <hip/hip_runtime.h>

#define NNODES 50000
#define NEDGES 800000
#define DIM 128
#define NGRAPHS 128
#define OUT1_STRIDE 384   // 3 layers * 128 concat along axis 1
#define OUT0_ELEMS (NGRAPHS * OUT1_STRIDE)
#define SCAN_CHUNK 512
#define ROWPAD 50048      // 64-aligned node row allocation (includes sentinel row N)

typedef unsigned int uint;
typedef unsigned short ushort;
typedef short bf16x8 __attribute__((ext_vector_type(8)));
typedef float f32x4 __attribute__((ext_vector_type(4)));

union U4 { uint4 u; bf16x8 h; };

__device__ inline uint rne_bf16(float f) {
    uint b = __float_as_uint(f);
    return (b + 0x7fffu + ((b >> 16) & 1u)) >> 16;
}
__device__ inline uint pack_bf16(float lo, float hi) {
    return rne_bf16(lo) | (rne_bf16(hi) << 16);
}
__device__ inline float blo(uint u) { return __uint_as_float(u << 16); }
__device__ inline float bhi(uint u) { return __uint_as_float(u & 0xffff0000u); }

// ---------- pre: W swizzle (blocks 0..23) + zero rowcnt/out0/sentinel + ginv ----------
// W -> MFMA B-fragment bf16: frag f = kblk*8+ntile, lane, j:
//   value = W[kblk*32 + (lane>>4)*8 + j][ntile*16 + (lane&15)]
__global__ __launch_bounds__(256) void k_pre(const float* __restrict__ W0,
                                             const float* __restrict__ W1,
                                             const float* __restrict__ W2,
                                             uint* __restrict__ wz,
                                             int* __restrict__ rowcnt,
                                             uint* __restrict__ hb,
                                             float* __restrict__ out0,
                                             float* __restrict__ ginv,
                                             const int* __restrict__ batch, int N) {
    if (blockIdx.x >= 24) {
        int i = (blockIdx.x - 24) * 256 + threadIdx.x;
        if (i < N) rowcnt[i] = 0;
        if (i < 64) hb[(size_t)N * 64 + i] = 0;   // sentinel row for masked gathers
        if (i < OUT0_ELEMS) out0[i] = 0.0f;       // atomic pool target
        if (blockIdx.x == 24 && threadIdx.x < NGRAPHS) {
            int g = threadIdx.x;                  // per-graph node count via bsearch
            int lo = 0, hi = N;
            while (lo < hi) { int mid = (lo + hi) >> 1; if (batch[mid] < g) lo = mid + 1; else hi = mid; }
            int b = lo;
            hi = N;
            while (lo < hi) { int mid = (lo + hi) >> 1; if (batch[mid] < g + 1) lo = mid + 1; else hi = mid; }
            ginv[g] = 1.0f / fmaxf((float)(lo - b), 1.0f);
        }
        return;
    }
    int layer = blockIdx.x >> 3;
    const float* W = (layer == 0) ? W0 : ((layer == 1) ? W1 : W2);
    int t = (blockIdx.x & 7) * 256 + threadIdx.x;  // chunk id 0..2047
    int f = t >> 6, lane = t & 63;
    int kb = f >> 3, nt = f & 7;
    int q = lane >> 4, m = lane & 15;
    int col = nt * 16 + m;
    uint v[8];
#pragma unroll
    for (int j = 0; j < 8; ++j)
        v[j] = rne_bf16(W[(kb * 32 + q * 8 + j) * 128 + col]);
    uint4 o;
    o.x = v[0] | (v[1] << 16);
    o.y = v[2] | (v[3] << 16);
    o.z = v[4] | (v[5] << 16);
    o.w = v[6] | (v[7] << 16);
    ((uint4*)wz)[layer * 2048 + t] = o;
}

// ---------- CSR build (two-pass: atomic-return rank, then non-atomic fill) ----------
__global__ void k_count(const int* __restrict__ dst, int* __restrict__ rowcnt,
                        int* __restrict__ rank, int E) {
    int e = blockIdx.x * blockDim.x + threadIdx.x;
    if (e < E) rank[e] = atomicAdd(&rowcnt[dst[e]], 1);
}

__global__ __launch_bounds__(512) void k_sum(const int* __restrict__ cnt,
                                             int* __restrict__ bsum,
                                             float* __restrict__ dinv, int n) {
    __shared__ int red[512];
    int t = threadIdx.x;
    int i = blockIdx.x * SCAN_CHUNK + t;
    int c = (i < n) ? cnt[i] : 0;
    if (i < n) dinv[i] = rsqrtf((float)c + 1.0f);  // +1 self-loop
    red[t] = c;
    __syncthreads();
    for (int off = 256; off > 0; off >>= 1) {
        if (t < off) red[t] += red[t + off];
        __syncthreads();
    }
    if (t == 0) bsum[blockIdx.x] = red[0];
}

// merged: per-block 512-scan + in-kernel 128-wide bsum scan (replaces k_scanb).
__global__ __launch_bounds__(512) void k_writeptr(const int* __restrict__ cnt,
                                                  const int* __restrict__ bsum,
                                                  int* __restrict__ rowptr,
                                                  int n, int nb) {
    __shared__ int s[512];
    __shared__ int sb[128];
    int t = threadIdx.x;
    if (t < 128) sb[t] = (t < nb) ? bsum[t] : 0;
    __syncthreads();
    for (int off = 1; off < 128; off <<= 1) {
        int u = (t < 128 && t >= off) ? sb[t - off] : 0;
        __syncthreads();
        if (t < 128) sb[t] += u;
        __syncthreads();
    }
    int boffb = (blockIdx.x == 0) ? 0 : sb[blockIdx.x - 1];  // exclusive block offset
    int i = blockIdx.x * SCAN_CHUNK + t;
    int v = (i < n) ? cnt[i] : 0;
    s[t] = v;
    __syncthreads();
    for (int off = 1; off < 512; off <<= 1) {
        int u = (t >= off) ? s[t - off] : 0;
        __syncthreads();
        s[t] += u;
        __syncthreads();
    }
    if (i < n) rowptr[i] = boffb + s[t] - v;
    if (i == n - 1) rowptr[n] = boffb + s[t];
}

__global__ void k_fill(const int* __restrict__ src, const int* __restrict__ dst,
                       const int* __restrict__ rowptr, const int* __restrict__ rank,
                       int* __restrict__ csr_src, int E) {
    int e = blockIdx.x * blockDim.x + threadIdx.x;
    if (e < E) {
        int d = dst[e];
        csr_src[rowptr[d] + rank[e]] = src[e];
    }
}

// ---------- MFMA GEMM: hb[M x 128 bf16] = dinv[row] * (A[M x 128 f32] @ W) ----------
__global__ __launch_bounds__(256) void k_gemm(const float* __restrict__ A, int lda,
                                              const uint* __restrict__ Wswz,
                                              const float* __restrict__ dinv,
                                              uint* __restrict__ hb, int M) {
    __shared__ uint4 wsw[2048];       // 32 KB swizzled W
    __shared__ ushort cbuf[64 * 128]; // 16 KB C bounce
    int tid = threadIdx.x;
#pragma unroll
    for (int i = 0; i < 8; ++i)
        wsw[i * 256 + tid] = ((const uint4*)Wswz)[i * 256 + tid];
    __syncthreads();
    int wave = tid >> 6, lane = tid & 63;
    int q = lane >> 4, m = lane & 15;
    int row0 = blockIdx.x * 64 + wave * 16;
    int arow = min(row0 + m, M - 1);       // clamp; stores are guarded
    const float* Ar = A + (size_t)arow * lda + q * 8;
    f32x4 zero = {0.0f, 0.0f, 0.0f, 0.0f};
    f32x4 acc[8];
#pragma unroll
    for (int i = 0; i < 8; ++i) acc[i] = zero;
#pragma unroll
    for (int kb = 0; kb < 4; ++kb) {
        float4 f0 = *(const float4*)(Ar + kb * 32);
        float4 f1 = *(const float4*)(Ar + kb * 32 + 4);
        U4 a;
        a.u.x = pack_bf16(f0.x, f0.y);
        a.u.y = pack_bf16(f0.z, f0.w);
        a.u.z = pack_bf16(f1.x, f1.y);
        a.u.w = pack_bf16(f1.z, f1.w);
#pragma unroll
        for (int nt = 0; nt < 8; ++nt) {
            U4 b; b.u = wsw[(kb * 8 + nt) * 64 + lane];
            acc[nt] = __builtin_amdgcn_mfma_f32_16x16x32_bf16(a.h, b.h, acc[nt], 0, 0, 0);
        }
    }
    // C/D: col = nt*16 + m, row = q*4 + r ; scale row r by dinv[row0+q*4+r]
    float dv[4];
#pragma unroll
    for (int r = 0; r < 4; ++r)
        dv[r] = dinv[min(row0 + q * 4 + r, M - 1)];
    ushort* cw = cbuf + wave * 16 * 128;
#pragma unroll
    for (int nt = 0; nt < 8; ++nt)
#pragma unroll
        for (int r = 0; r < 4; ++r)
            cw[(q * 4 + r) * 128 + nt * 16 + m] = (ushort)rne_bf16(acc[nt][r] * dv[r]);
    __syncthreads();
    const uint4* cr4 = (const uint4*)cbuf;
#pragma unroll
    for (int i = 0; i < 4; ++i) {
        int c = (wave * 256) + i * 64 + lane;  // chunk: row = c>>4, piece = c&15
        int grow = blockIdx.x * 64 + (c >> 4);
        uint4 v = cr4[c];
        if (grow < M) ((uint4*)hb)[(size_t)grow * 16 + (c & 15)] = v;
    }
}

// ---------- fused aggregate + bias + relu + write out1 + atomic mean-pool ----------
// one wave per node (R2-proven form). Lane layout: g16 = lane>>4 owns edge slot,
// m16 = lane&15 owns 8 channels (one uint4 = 16B of the 256B row). One gather
// instruction covers 4 edges x full row; NO cross-lane shuffles in the edge loop.
// Out-of-range edge slots read the zeroed sentinel row (index N).
// Pool fusion: each lane atomically adds its 2 final channels (pre-scaled by
// 1/cnt[graph]) into out0 — replaces the separate 76.8MB k_pool pass.
__global__ __launch_bounds__(256) void k_agg(const uint* __restrict__ hb,
                                             const int* __restrict__ rowptr,
                                             const int* __restrict__ csr_src,
                                             const float* __restrict__ dinv,
                                             const float* __restrict__ bias,
                                             const int* __restrict__ batch,
                                             const float* __restrict__ ginv,
                                             float* __restrict__ out0,
                                             float* __restrict__ out1,
                                             int N, int layer) {
    int wave = threadIdx.x >> 6;
    int lane = threadIdx.x & 63;
    int n = blockIdx.x * 4 + wave;
    if (n >= N) return;
    int g16 = lane >> 4;
    int m16 = lane & 15;
    const uint4* hb4 = (const uint4*)hb;

    // self-loop: hb already holds dinv[n]*h[n]; count it once (group 0 only)
    uint4 su = hb4[(size_t)n * 16 + m16];
    float sel = (g16 == 0) ? 1.0f : 0.0f;
    float a0 = sel * blo(su.x), a1 = sel * bhi(su.x);
    float a2 = sel * blo(su.y), a3 = sel * bhi(su.y);
    float a4 = sel * blo(su.z), a5 = sel * bhi(su.z);
    float a6 = sel * blo(su.w), a7 = sel * bhi(su.w);

    int beg = rowptr[n], end = rowptr[n + 1];
    for (int base = beg; base < end; base += 16) {
        int s0, s1, s2, s3;
        {
            int e0 = base + 0 + g16;
            int e1 = base + 4 + g16;
            int e2 = base + 8 + g16;
            int e3 = base + 12 + g16;
            s0 = (e0 < end) ? csr_src[e0] : N;
            s1 = (e1 < end) ? csr_src[min(e1, end - 1)] : N;
            s2 = (e2 < end) ? csr_src[min(e2, end - 1)] : N;
            s3 = (e3 < end) ? csr_src[min(e3, end - 1)] : N;
        }
        uint4 u0 = hb4[(size_t)s0 * 16 + m16];
        uint4 u1 = hb4[(size_t)s1 * 16 + m16];
        uint4 u2 = hb4[(size_t)s2 * 16 + m16];
        uint4 u3 = hb4[(size_t)s3 * 16 + m16];
        a0 += blo(u0.x); a1 += bhi(u0.x); a2 += blo(u0.y); a3 += bhi(u0.y);
        a4 += blo(u0.z); a5 += bhi(u0.z); a6 += blo(u0.w); a7 += bhi(u0.w);
        a0 += blo(u1.x); a1 += bhi(u1.x); a2 += blo(u1.y); a3 += bhi(u1.y);
        a4 += blo(u1.z); a5 += bhi(u1.z); a6 += blo(u1.w); a7 += bhi(u1.w);
        a0 += blo(u2.x); a1 += bhi(u2.x); a2 += blo(u2.y); a3 += bhi(u2.y);
        a4 += blo(u2.z); a5 += bhi(u2.z); a6 += blo(u2.w); a7 += bhi(u2.w);
        a0 += blo(u3.x); a1 += bhi(u3.x); a2 += blo(u3.y); a3 += bhi(u3.y);
        a4 += blo(u3.z); a5 += bhi(u3.z); a6 += blo(u3.w); a7 += bhi(u3.w);
    }

    // cross-group reduce: groups 0..3 hold partial sums of the same 8 channels
#pragma unroll
    for (int d = 16; d < 64; d <<= 1) {
        a0 += __shfl_xor(a0, d); a1 += __shfl_xor(a1, d);
        a2 += __shfl_xor(a2, d); a3 += __shfl_xor(a3, d);
        a4 += __shfl_xor(a4, d); a5 += __shfl_xor(a5, d);
        a6 += __shfl_xor(a6, d); a7 += __shfl_xor(a7, d);
    }

    // lane writes channel pair c = m16*8 + g16*2  (compile-time acc selection)
    float vx = (g16 == 0) ? a0 : (g16 == 1) ? a2 : (g16 == 2) ? a4 : a6;
    float vy = (g16 == 0) ? a1 : (g16 == 1) ? a3 : (g16 == 2) ? a5 : a7;
    float din = dinv[n];
    int c = m16 * 8 + g16 * 2;
    float2 b = ((const float2*)bias)[m16 * 4 + g16];
    float ox = fmaxf(din * vx + b.x, 0.0f);
    float oy = fmaxf(din * vy + b.y, 0.0f);
    size_t o1 = (size_t)n * OUT1_STRIDE + layer * DIM + c;
    *(float2*)(out1 + o1) = make_float2(ox, oy);

    // fused mean-pool: pre-scaled atomic accumulate into this graph's pooled row
    int gg = batch[n];
    float gi = ginv[gg];
    float* o0 = out0 + (size_t)gg * OUT1_STRIDE + layer * DIM + c;
    atomicAdd(o0, ox * gi);
    atomicAdd(o0 + 1, oy * gi);
}

extern "C" void kernel_launch(void* const* d_in, const int* in_sizes, int n_in,
                              void* d_out, int out_size, void* d_ws, size_t ws_size,
                              hipStream_t stream) {
    const float* x     = (const float*)d_in[0];
    const int*   ei    = (const int*)d_in[1];
    const int*   batch = (const int*)d_in[2];
    const float* W0 = (const float*)d_in[3];
    const float* b0 = (const float*)d_in[4];
    const float* W1 = (const float*)d_in[5];
    const float* b1 = (const float*)d_in[6];
    const float* W2 = (const float*)d_in[7];
    const float* b2 = (const float*)d_in[8];
    (void)n_in; (void)ws_size; (void)out_size;

    const int E = in_sizes[1] / 2;
    const int N = in_sizes[2];
    const int* src = ei;
    const int* dst = ei + E;

    char* ws = (char*)d_ws;
    uint*  hb       = (uint*)ws;  ws += (size_t)ROWPAD * 64 * 4;   // bf16 dinv*h@W (+sentinel)
    uint*  wz       = (uint*)ws;  ws += 3 * 8192 * 4;              // swizzled W ×3
    float* dinv     = (float*)ws; ws += 50016 * 4;
    int*   rowcnt   = (int*)ws;   ws += 50016 * 4;
    int*   rowptr   = (int*)ws;   ws += 50016 * 4;
    int*   rank     = (int*)ws;   ws += (size_t)NEDGES * 4;
    int*   csr_src  = (int*)ws;   ws += (size_t)NEDGES * 4;
    int*   bsum     = (int*)ws;   ws += 256 * 4;
    float* ginv     = (float*)ws; ws += 128 * 4;

    float* out0 = (float*)d_out;                 // [128, 384] pooled (atomic target)
    float* out1 = (float*)d_out + OUT0_ELEMS;    // [50000, 384] per-layer features

    const int nb  = (N + SCAN_CHUNK - 1) / SCAN_CHUNK;  // 98
    const int nbz = 24 + (N + 255) / 256;               // pre: 24 wswz + zero blocks

    k_pre     <<<nbz, 256, 0, stream>>>(W0, W1, W2, wz, rowcnt, hb, out0, ginv, batch, N);
    k_count   <<<(E + 255) / 256, 256, 0, stream>>>(dst, rowcnt, rank, E);
    k_sum     <<<nb, 512, 0, stream>>>(rowcnt, bsum, dinv, N);
    k_writeptr<<<nb, 512, 0, stream>>>(rowcnt, bsum, rowptr, N, nb);
    k_fill    <<<(E + 255) / 256, 256, 0, stream>>>(src, dst, rowptr, rank, csr_src, E);

    const float* bs[3] = {b0, b1, b2};
    const int ngb = (N + 63) / 64;   // 782 gemm blocks
    for (int l = 0; l < 3; ++l) {
        const float* Ain = (l == 0) ? x : (out1 + (size_t)(l - 1) * DIM);
        int lda          = (l == 0) ? DIM : OUT1_STRIDE;
        k_gemm<<<ngb, 256, 0, stream>>>(Ain, lda, wz + l * 8192, dinv, hb, N);
        k_agg <<<(N + 3) / 4, 256, 0, stream>>>(hb, rowptr, csr_src, dinv, bs[l],
                                                batch, ginv, out0, out1, N, l);
    }
}

// Round 11
// 309.227 us; speedup vs baseline: 1.8728x; 1.8728x over previous
//
#include <hip/hip_runtime.h>

#define NNODES 50000
#define NEDGES 800000
#define DIM 128
#define NGRAPHS 128
#define OUT1_STRIDE 384   // 3 layers * 128 concat along axis 1
#define OUT0_ELEMS (NGRAPHS * OUT1_STRIDE)
#define SCAN_CHUNK 512
#define ROWPAD 50048      // 64-aligned node row allocation (includes sentinel row N)

typedef unsigned int uint;
typedef unsigned short ushort;
typedef short bf16x8 __attribute__((ext_vector_type(8)));
typedef float f32x4 __attribute__((ext_vector_type(4)));

union U4 { uint4 u; bf16x8 h; };

__device__ inline uint rne_bf16(float f) {
    uint b = __float_as_uint(f);
    return (b + 0x7fffu + ((b >> 16) & 1u)) >> 16;
}
__device__ inline uint pack_bf16(float lo, float hi) {
    return rne_bf16(lo) | (rne_bf16(hi) << 16);
}
__device__ inline float blo(uint u) { return __uint_as_float(u << 16); }
__device__ inline float bhi(uint u) { return __uint_as_float(u & 0xffff0000u); }

// ---------- pre: W swizzle (blocks 0..23) + rowcnt zero + hb sentinel zero ----------
// W -> MFMA B-fragment bf16: frag f = kblk*8+ntile, lane, j:
//   value = W[kblk*32 + (lane>>4)*8 + j][ntile*16 + (lane&15)]
__global__ __launch_bounds__(256) void k_pre(const float* __restrict__ W0,
                                             const float* __restrict__ W1,
                                             const float* __restrict__ W2,
                                             uint* __restrict__ wz,
                                             int* __restrict__ rowcnt,
                                             uint* __restrict__ hb, int N) {
    if (blockIdx.x >= 24) {
        int i = (blockIdx.x - 24) * 256 + threadIdx.x;
        if (i < N) rowcnt[i] = 0;
        if (i < 64) hb[(size_t)N * 64 + i] = 0;  // sentinel row for masked gathers
        return;
    }
    int layer = blockIdx.x >> 3;
    const float* W = (layer == 0) ? W0 : ((layer == 1) ? W1 : W2);
    int t = (blockIdx.x & 7) * 256 + threadIdx.x;  // chunk id 0..2047
    int f = t >> 6, lane = t & 63;
    int kb = f >> 3, nt = f & 7;
    int q = lane >> 4, m = lane & 15;
    int col = nt * 16 + m;
    uint v[8];
#pragma unroll
    for (int j = 0; j < 8; ++j)
        v[j] = rne_bf16(W[(kb * 32 + q * 8 + j) * 128 + col]);
    uint4 o;
    o.x = v[0] | (v[1] << 16);
    o.y = v[2] | (v[3] << 16);
    o.z = v[4] | (v[5] << 16);
    o.w = v[6] | (v[7] << 16);
    ((uint4*)wz)[layer * 2048 + t] = o;
}

// ---------- CSR build (two-pass: atomic-return rank, then non-atomic fill) ----------
__global__ void k_count(const int* __restrict__ dst, int* __restrict__ rowcnt,
                        int* __restrict__ rank, int E) {
    int e = blockIdx.x * blockDim.x + threadIdx.x;
    if (e < E) rank[e] = atomicAdd(&rowcnt[dst[e]], 1);
}

__global__ __launch_bounds__(512) void k_sum(const int* __restrict__ cnt,
                                             int* __restrict__ bsum,
                                             float* __restrict__ dinv, int n) {
    __shared__ int red[512];
    int t = threadIdx.x;
    int i = blockIdx.x * SCAN_CHUNK + t;
    int c = (i < n) ? cnt[i] : 0;
    if (i < n) dinv[i] = rsqrtf((float)c + 1.0f);  // +1 self-loop
    red[t] = c;
    __syncthreads();
    for (int off = 256; off > 0; off >>= 1) {
        if (t < off) red[t] += red[t + off];
        __syncthreads();
    }
    if (t == 0) bsum[blockIdx.x] = red[0];
}

// merged: per-block 512-scan + in-kernel 128-wide bsum scan (replaces k_scanb).
__global__ __launch_bounds__(512) void k_writeptr(const int* __restrict__ cnt,
                                                  const int* __restrict__ bsum,
                                                  int* __restrict__ rowptr,
                                                  int n, int nb) {
    __shared__ int s[512];
    __shared__ int sb[128];
    int t = threadIdx.x;
    if (t < 128) sb[t] = (t < nb) ? bsum[t] : 0;
    __syncthreads();
    for (int off = 1; off < 128; off <<= 1) {
        int u = (t < 128 && t >= off) ? sb[t - off] : 0;
        __syncthreads();
        if (t < 128) sb[t] += u;
        __syncthreads();
    }
    int boffb = (blockIdx.x == 0) ? 0 : sb[blockIdx.x - 1];  // exclusive block offset
    int i = blockIdx.x * SCAN_CHUNK + t;
    int v = (i < n) ? cnt[i] : 0;
    s[t] = v;
    __syncthreads();
    for (int off = 1; off < 512; off <<= 1) {
        int u = (t >= off) ? s[t - off] : 0;
        __syncthreads();
        s[t] += u;
        __syncthreads();
    }
    if (i < n) rowptr[i] = boffb + s[t] - v;
    if (i == n - 1) rowptr[n] = boffb + s[t];
}

__global__ void k_fill(const int* __restrict__ src, const int* __restrict__ dst,
                       const int* __restrict__ rowptr, const int* __restrict__ rank,
                       int* __restrict__ csr_src, int E) {
    int e = blockIdx.x * blockDim.x + threadIdx.x;
    if (e < E) {
        int d = dst[e];
        csr_src[rowptr[d] + rank[e]] = src[e];
    }
}

// ---------- MFMA GEMM: hb[M x 128 bf16] = dinv[row] * (A[M x 128 f32] @ W) ----------
__global__ __launch_bounds__(256) void k_gemm(const float* __restrict__ A, int lda,
                                              const uint* __restrict__ Wswz,
                                              const float* __restrict__ dinv,
                                              uint* __restrict__ hb, int M) {
    __shared__ uint4 wsw[2048];       // 32 KB swizzled W
    __shared__ ushort cbuf[64 * 128]; // 16 KB C bounce
    int tid = threadIdx.x;
#pragma unroll
    for (int i = 0; i < 8; ++i)
        wsw[i * 256 + tid] = ((const uint4*)Wswz)[i * 256 + tid];
    __syncthreads();
    int wave = tid >> 6, lane = tid & 63;
    int q = lane >> 4, m = lane & 15;
    int row0 = blockIdx.x * 64 + wave * 16;
    int arow = min(row0 + m, M - 1);       // clamp; stores are guarded
    const float* Ar = A + (size_t)arow * lda + q * 8;
    f32x4 zero = {0.0f, 0.0f, 0.0f, 0.0f};
    f32x4 acc[8];
#pragma unroll
    for (int i = 0; i < 8; ++i) acc[i] = zero;
#pragma unroll
    for (int kb = 0; kb < 4; ++kb) {
        float4 f0 = *(const float4*)(Ar + kb * 32);
        float4 f1 = *(const float4*)(Ar + kb * 32 + 4);
        U4 a;
        a.u.x = pack_bf16(f0.x, f0.y);
        a.u.y = pack_bf16(f0.z, f0.w);
        a.u.z = pack_bf16(f1.x, f1.y);
        a.u.w = pack_bf16(f1.z, f1.w);
#pragma unroll
        for (int nt = 0; nt < 8; ++nt) {
            U4 b; b.u = wsw[(kb * 8 + nt) * 64 + lane];
            acc[nt] = __builtin_amdgcn_mfma_f32_16x16x32_bf16(a.h, b.h, acc[nt], 0, 0, 0);
        }
    }
    // C/D: col = nt*16 + m, row = q*4 + r ; scale row r by dinv[row0+q*4+r]
    float dv[4];
#pragma unroll
    for (int r = 0; r < 4; ++r)
        dv[r] = dinv[min(row0 + q * 4 + r, M - 1)];
    ushort* cw = cbuf + wave * 16 * 128;
#pragma unroll
    for (int nt = 0; nt < 8; ++nt)
#pragma unroll
        for (int r = 0; r < 4; ++r)
            cw[(q * 4 + r) * 128 + nt * 16 + m] = (ushort)rne_bf16(acc[nt][r] * dv[r]);
    __syncthreads();
    const uint4* cr4 = (const uint4*)cbuf;
#pragma unroll
    for (int i = 0; i < 4; ++i) {
        int c = (wave * 256) + i * 64 + lane;  // chunk: row = c>>4, piece = c&15
        int grow = blockIdx.x * 64 + (c >> 4);
        uint4 v = cr4[c];
        if (grow < M) ((uint4*)hb)[(size_t)grow * 16 + (c & 15)] = v;
    }
}

// ---------- fused aggregate + bias + relu + write out1 (R2-proven form) ----------
// one wave per node. Lane layout: g16 = lane>>4 owns edge slot, m16 = lane&15 owns
// 8 channels (one uint4 = 16B of the 256B row). One gather instruction covers
// 4 edges x full row; NO cross-lane shuffles in the edge loop. Out-of-range edge
// slots read the zeroed sentinel row (index N).
__global__ __launch_bounds__(256) void k_agg(const uint* __restrict__ hb,
                                             const int* __restrict__ rowptr,
                                             const int* __restrict__ csr_src,
                                             const float* __restrict__ dinv,
                                             const float* __restrict__ bias,
                                             float* __restrict__ out1,
                                             int N, int layer) {
    int wave = threadIdx.x >> 6;
    int lane = threadIdx.x & 63;
    int n = blockIdx.x * 4 + wave;
    if (n >= N) return;
    int g16 = lane >> 4;
    int m16 = lane & 15;
    const uint4* hb4 = (const uint4*)hb;

    // self-loop: hb already holds dinv[n]*h[n]; count it once (group 0 only)
    uint4 su = hb4[(size_t)n * 16 + m16];
    float sel = (g16 == 0) ? 1.0f : 0.0f;
    float a0 = sel * blo(su.x), a1 = sel * bhi(su.x);
    float a2 = sel * blo(su.y), a3 = sel * bhi(su.y);
    float a4 = sel * blo(su.z), a5 = sel * bhi(su.z);
    float a6 = sel * blo(su.w), a7 = sel * bhi(su.w);

    int beg = rowptr[n], end = rowptr[n + 1];
    for (int base = beg; base < end; base += 16) {
        int s0, s1, s2, s3;
        {
            int e0 = base + 0 + g16;
            int e1 = base + 4 + g16;
            int e2 = base + 8 + g16;
            int e3 = base + 12 + g16;
            s0 = (e0 < end) ? csr_src[e0] : N;
            s1 = (e1 < end) ? csr_src[min(e1, end - 1)] : N;
            s2 = (e2 < end) ? csr_src[min(e2, end - 1)] : N;
            s3 = (e3 < end) ? csr_src[min(e3, end - 1)] : N;
        }
        uint4 u0 = hb4[(size_t)s0 * 16 + m16];
        uint4 u1 = hb4[(size_t)s1 * 16 + m16];
        uint4 u2 = hb4[(size_t)s2 * 16 + m16];
        uint4 u3 = hb4[(size_t)s3 * 16 + m16];
        a0 += blo(u0.x); a1 += bhi(u0.x); a2 += blo(u0.y); a3 += bhi(u0.y);
        a4 += blo(u0.z); a5 += bhi(u0.z); a6 += blo(u0.w); a7 += bhi(u0.w);
        a0 += blo(u1.x); a1 += bhi(u1.x); a2 += blo(u1.y); a3 += bhi(u1.y);
        a4 += blo(u1.z); a5 += bhi(u1.z); a6 += blo(u1.w); a7 += bhi(u1.w);
        a0 += blo(u2.x); a1 += bhi(u2.x); a2 += blo(u2.y); a3 += bhi(u2.y);
        a4 += blo(u2.z); a5 += bhi(u2.z); a6 += blo(u2.w); a7 += bhi(u2.w);
        a0 += blo(u3.x); a1 += bhi(u3.x); a2 += blo(u3.y); a3 += bhi(u3.y);
        a4 += blo(u3.z); a5 += bhi(u3.z); a6 += blo(u3.w); a7 += bhi(u3.w);
    }

    // cross-group reduce: groups 0..3 hold partial sums of the same 8 channels
#pragma unroll
    for (int d = 16; d < 64; d <<= 1) {
        a0 += __shfl_xor(a0, d); a1 += __shfl_xor(a1, d);
        a2 += __shfl_xor(a2, d); a3 += __shfl_xor(a3, d);
        a4 += __shfl_xor(a4, d); a5 += __shfl_xor(a5, d);
        a6 += __shfl_xor(a6, d); a7 += __shfl_xor(a7, d);
    }

    // lane writes channel pair c = m16*8 + g16*2  (compile-time acc selection)
    float vx = (g16 == 0) ? a0 : (g16 == 1) ? a2 : (g16 == 2) ? a4 : a6;
    float vy = (g16 == 0) ? a1 : (g16 == 1) ? a3 : (g16 == 2) ? a5 : a7;
    float din = dinv[n];
    float2 b = ((const float2*)bias)[m16 * 4 + g16];
    float ox = fmaxf(din * vx + b.x, 0.0f);
    float oy = fmaxf(din * vy + b.y, 0.0f);
    size_t o1 = (size_t)n * OUT1_STRIDE + layer * DIM + (m16 * 8 + g16 * 2);
    *(float2*)(out1 + o1) = make_float2(ox, oy);
}

// ---------- mean-pool: 3 blocks per graph (128-ch chunk each), 2 row-slices ----------
__global__ __launch_bounds__(256) void k_pool(const float* __restrict__ out1,
                                              const int* __restrict__ batch,
                                              float* __restrict__ out0, int N) {
    int g = blockIdx.x / 3;
    int chunk = blockIdx.x % 3;
    int lo = 0, hi = N;
    while (lo < hi) { int mid = (lo + hi) >> 1; if (batch[mid] < g) lo = mid + 1; else hi = mid; }
    int beg = lo;
    hi = N;
    while (lo < hi) { int mid = (lo + hi) >> 1; if (batch[mid] < g + 1) lo = mid + 1; else hi = mid; }
    int end = lo;
    int t = threadIdx.x;
    int ch = t & 127;
    int slice = t >> 7;            // 0 or 1: even/odd rows
    const float* p = out1 + (size_t)chunk * 128 + ch;
    float acc = 0.0f;
    int i = beg + slice;
    for (; i + 6 < end; i += 8) {  // stride-2 rows, 4-way MLP unroll
        float a0 = p[(size_t)i * OUT1_STRIDE];
        float a1 = p[(size_t)(i + 2) * OUT1_STRIDE];
        float a2 = p[(size_t)(i + 4) * OUT1_STRIDE];
        float a3 = p[(size_t)(i + 6) * OUT1_STRIDE];
        acc += (a0 + a1) + (a2 + a3);
    }
    for (; i < end; i += 2) acc += p[(size_t)i * OUT1_STRIDE];
    __shared__ float red[256];
    red[t] = acc;
    __syncthreads();
    if (t < 128) {
        float tot = red[t] + red[t + 128];
        float cnt = (float)(end - beg);
        out0[(size_t)g * OUT1_STRIDE + chunk * 128 + t] = tot / fmaxf(cnt, 1.0f);
    }
}

extern "C" void kernel_launch(void* const* d_in, const int* in_sizes, int n_in,
                              void* d_out, int out_size, void* d_ws, size_t ws_size,
                              hipStream_t stream) {
    const float* x     = (const float*)d_in[0];
    const int*   ei    = (const int*)d_in[1];
    const int*   batch = (const int*)d_in[2];
    const float* W0 = (const float*)d_in[3];
    const float* b0 = (const float*)d_in[4];
    const float* W1 = (const float*)d_in[5];
    const float* b1 = (const float*)d_in[6];
    const float* W2 = (const float*)d_in[7];
    const float* b2 = (const float*)d_in[8];
    (void)n_in; (void)ws_size; (void)out_size;

    const int E = in_sizes[1] / 2;
    const int N = in_sizes[2];
    const int* src = ei;
    const int* dst = ei + E;

    char* ws = (char*)d_ws;
    uint*  hb       = (uint*)ws;  ws += (size_t)ROWPAD * 64 * 4;   // bf16 dinv*h@W (+sentinel)
    uint*  wz       = (uint*)ws;  ws += 3 * 8192 * 4;              // swizzled W ×3
    float* dinv     = (float*)ws; ws += 50016 * 4;
    int*   rowcnt   = (int*)ws;   ws += 50016 * 4;
    int*   rowptr   = (int*)ws;   ws += 50016 * 4;
    int*   rank     = (int*)ws;   ws += (size_t)NEDGES * 4;
    int*   csr_src  = (int*)ws;   ws += (size_t)NEDGES * 4;
    int*   bsum     = (int*)ws;   ws += 256 * 4;

    float* out0 = (float*)d_out;                 // [128, 384] pooled
    float* out1 = (float*)d_out + OUT0_ELEMS;    // [50000, 384] per-layer features

    const int nb  = (N + SCAN_CHUNK - 1) / SCAN_CHUNK;  // 98
    const int nbz = 24 + (N + 255) / 256;               // pre: 24 wswz + zero blocks

    k_pre     <<<nbz, 256, 0, stream>>>(W0, W1, W2, wz, rowcnt, hb, N);
    k_count   <<<(E + 255) / 256, 256, 0, stream>>>(dst, rowcnt, rank, E);
    k_sum     <<<nb, 512, 0, stream>>>(rowcnt, bsum, dinv, N);
    k_writeptr<<<nb, 512, 0, stream>>>(rowcnt, bsum, rowptr, N, nb);
    k_fill    <<<(E + 255) / 256, 256, 0, stream>>>(src, dst, rowptr, rank, csr_src, E);

    const float* bs[3] = {b0, b1, b2};
    const int ngb = (N + 63) / 64;   // 782 gemm blocks
    for (int l = 0; l < 3; ++l) {
        const float* Ain = (l == 0) ? x : (out1 + (size_t)(l - 1) * DIM);
        int lda          = (l == 0) ? DIM : OUT1_STRIDE;
        k_gemm<<<ngb, 256, 0, stream>>>(Ain, lda, wz + l * 8192, dinv, hb, N);
        k_agg <<<(N + 3) / 4, 256, 0, stream>>>(hb, rowptr, csr_src, dinv,
                                                bs[l], out1, N, l);
    }
    k_pool<<<NGRAPHS * 3, 256, 0, stream>>>(out1, batch, out0, N);
}